// Round 1
// baseline (876.427 us; speedup 1.0000x reference)
//
#include <hip/hip_runtime.h>
#include <math.h>

// ---------------------------------------------------------------------------
// GATRegressor: 2x GATConv(128->128, heads=1, self-loops) + max/mean pool + FC
// N=50000 nodes, E=1.6M edges, G=512 graphs. fp32 throughout.
// Strategy: build CSR (dst-major) once per launch; per layer:
//   gemm (x@W) -> rowdots (asrc/adst) -> wave-per-dst softmax-aggregate.
// ---------------------------------------------------------------------------

#define LEAKY 0.2f

__global__ __launch_bounds__(256) void initk(int* counts, int* gcount, int N, int G) {
    int i = blockIdx.x * 256 + threadIdx.x;
    if (i < N) counts[i] = 1;            // self-loop per node
    if (i < G) gcount[i] = 0;
}

__global__ __launch_bounds__(256) void histk(const int* __restrict__ ei,
                                             const int* __restrict__ batch,
                                             int* counts, int* gcount, int E, int N) {
    int i = blockIdx.x * 256 + threadIdx.x;
    if (i < E) atomicAdd(&counts[ei[E + i]], 1);   // dst row of edge_index
    if (i < N) atomicAdd(&gcount[batch[i]], 1);
}

// single-block exclusive scan, n <= 1024*chunk. writes out[0..n] (out[n]=total),
// optionally mirrors into out2 (cursor copy).
__global__ __launch_bounds__(1024) void scan_excl(const int* __restrict__ in,
                                                  int* __restrict__ out,
                                                  int* __restrict__ out2, int n) {
    __shared__ int sh[1024];
    int t = threadIdx.x;
    int chunk = (n + 1023) >> 10;
    int begin = t * chunk;
    int fin = begin + chunk; if (fin > n) fin = n;
    int s = 0;
    for (int i = begin; i < fin; ++i) s += in[i];
    sh[t] = s;
    __syncthreads();
    for (int off = 1; off < 1024; off <<= 1) {
        int v = (t >= off) ? sh[t - off] : 0;
        __syncthreads();
        sh[t] += v;
        __syncthreads();
    }
    int run = sh[t] - s;   // exclusive prefix
    for (int i = begin; i < fin; ++i) {
        out[i] = run;
        if (out2) out2[i] = run;
        run += in[i];
    }
    if (t == 1023) { out[n] = sh[1023]; }
}

__global__ __launch_bounds__(256) void scatterk(const int* __restrict__ ei,
                                                int* cursor, int* col, int E, int N) {
    int i = blockIdx.x * 256 + threadIdx.x;
    if (i < E) {
        int s = ei[i];
        int d = ei[E + i];
        col[atomicAdd(&cursor[d], 1)] = s;
    } else if (i < E + N) {
        int v = i - E;
        col[atomicAdd(&cursor[v], 1)] = v;   // self loop
    }
}

// C[n x 128] = act(A[n x 128]) @ B[128 x 128]; applyRelu relus A on load.
__global__ __launch_bounds__(256) void gemm128(const float* __restrict__ A,
                                               const float* __restrict__ B,
                                               float* __restrict__ C,
                                               int n, int applyRelu) {
    __shared__ float As[64][33];     // [m][k], +1 pad
    __shared__ float Bs[32][132];    // [k][c], +4 pad
    const int tid = threadIdx.x;
    const int row0 = blockIdx.x * 64;
    const int tx = tid & 15;         // col group, TN=8
    const int ty = tid >> 4;         // row group, TM=4
    float acc[4][8] = {};

    for (int k0 = 0; k0 < 128; k0 += 32) {
        // A tile: 64 rows x 32 k. thread: r = tid>>3 (+32), kv = tid&7 (float4)
        {
            int kv = tid & 7, r = tid >> 3;
#pragma unroll
            for (int i = 0; i < 2; ++i) {
                int rr = r + 32 * i;
                int grow = row0 + rr;
                float4 v = make_float4(0.f, 0.f, 0.f, 0.f);
                if (grow < n) v = *(const float4*)(A + (size_t)grow * 128 + k0 + kv * 4);
                if (applyRelu) {
                    v.x = fmaxf(v.x, 0.f); v.y = fmaxf(v.y, 0.f);
                    v.z = fmaxf(v.z, 0.f); v.w = fmaxf(v.w, 0.f);
                }
                As[rr][kv * 4 + 0] = v.x; As[rr][kv * 4 + 1] = v.y;
                As[rr][kv * 4 + 2] = v.z; As[rr][kv * 4 + 3] = v.w;
            }
        }
        // B tile: 32 k x 128 c. thread: kr = tid>>5 (+8*i), cv = tid&31 (float4)
        {
            int cv = tid & 31, kr = tid >> 5;
#pragma unroll
            for (int i = 0; i < 4; ++i) {
                int kk = kr + 8 * i;
                float4 v = *(const float4*)(B + (size_t)(k0 + kk) * 128 + cv * 4);
                Bs[kk][cv * 4 + 0] = v.x; Bs[kk][cv * 4 + 1] = v.y;
                Bs[kk][cv * 4 + 2] = v.z; Bs[kk][cv * 4 + 3] = v.w;
            }
        }
        __syncthreads();
#pragma unroll
        for (int k = 0; k < 32; ++k) {
            float a[4], b[8];
#pragma unroll
            for (int i = 0; i < 4; ++i) a[i] = As[ty * 4 + i][k];
#pragma unroll
            for (int j = 0; j < 8; ++j) b[j] = Bs[k][tx * 8 + j];
#pragma unroll
            for (int i = 0; i < 4; ++i)
#pragma unroll
                for (int j = 0; j < 8; ++j) acc[i][j] += a[i] * b[j];
        }
        __syncthreads();
    }
#pragma unroll
    for (int i = 0; i < 4; ++i) {
        int grow = row0 + ty * 4 + i;
        if (grow < n) {
            float4* dst = (float4*)(C + (size_t)grow * 128 + tx * 8);
            dst[0] = make_float4(acc[i][0], acc[i][1], acc[i][2], acc[i][3]);
            dst[1] = make_float4(acc[i][4], acc[i][5], acc[i][6], acc[i][7]);
        }
    }
}

// asrc[r] = h'[r,:]·a_src ; adst[r] = h'[r,:]·a_dst. one wave per row.
__global__ __launch_bounds__(256) void rowdots(const float* __restrict__ hp,
                                               const float* __restrict__ a_src,
                                               const float* __restrict__ a_dst,
                                               float* __restrict__ asv,
                                               float* __restrict__ adv, int n) {
    int w = (blockIdx.x * 256 + threadIdx.x) >> 6;
    int lane = threadIdx.x & 63;
    if (w >= n) return;
    float2 v = *(const float2*)(hp + (size_t)w * 128 + 2 * lane);
    float2 as = ((const float2*)a_src)[lane];
    float2 ad = ((const float2*)a_dst)[lane];
    float ps = v.x * as.x + v.y * as.y;
    float pd = v.x * ad.x + v.y * ad.y;
#pragma unroll
    for (int off = 32; off; off >>= 1) {
        ps += __shfl_xor(ps, off, 64);
        pd += __shfl_xor(pd, off, 64);
    }
    if (lane == 0) { asv[w] = ps; adv[w] = pd; }
}

// one wave per dst node: segment softmax over incoming edges + weighted feature sum.
// out[d,:] = relu( (sum_e exp(l_e - m) * h'[src_e,:]) / sum_e exp(l_e - m) + bias )
__global__ __launch_bounds__(256) void aggregate(const float* __restrict__ hp,
                                                 const int* __restrict__ rp,
                                                 const int* __restrict__ col,
                                                 const float* __restrict__ asv,
                                                 const float* __restrict__ adv,
                                                 const float* __restrict__ bias,
                                                 float* __restrict__ out, int n) {
    int w = (blockIdx.x * 256 + threadIdx.x) >> 6;
    int lane = threadIdx.x & 63;
    if (w >= n) return;
    int start = rp[w], end = rp[w + 1];
    float ad = adv[w];

    // phase A1: wave-max of leaky logits
    float m = -INFINITY;
    for (int e = start + lane; e < end; e += 64) {
        float l = asv[col[e]] + ad;
        l = l > 0.f ? l : LEAKY * l;
        m = fmaxf(m, l);
    }
#pragma unroll
    for (int off = 32; off; off >>= 1) m = fmaxf(m, __shfl_xor(m, off, 64));

    // phase A2: wave-sum of exp
    float ssum = 0.f;
    for (int e = start + lane; e < end; e += 64) {
        float l = asv[col[e]] + ad;
        l = l > 0.f ? l : LEAKY * l;
        ssum += __expf(l - m);
    }
#pragma unroll
    for (int off = 32; off; off >>= 1) ssum += __shfl_xor(ssum, off, 64);
    float inv = 1.f / ssum;

    // phase B: weighted feature accumulation (wave-wide coalesced row loads)
    float2 acc = make_float2(0.f, 0.f);
    for (int e = start; e < end; ++e) {
        int c = col[e];                   // wave-uniform
        float l = asv[c] + ad;
        l = l > 0.f ? l : LEAKY * l;
        float wgt = __expf(l - m);
        float2 v = *(const float2*)(hp + (size_t)c * 128 + 2 * lane);
        acc.x += wgt * v.x;
        acc.y += wgt * v.y;
    }
    float2 b = ((const float2*)bias)[lane];
    float2 o;
    o.x = fmaxf(acc.x * inv + b.x, 0.f);
    o.y = fmaxf(acc.y * inv + b.y, 0.f);
    *(float2*)(out + (size_t)w * 128 + 2 * lane) = o;
}

// one block (128 threads) per graph: max/mean pool over contiguous node range,
// then dot with fc_w (256) + fc_b.
__global__ __launch_bounds__(128) void poolfc(const float* __restrict__ h2,
                                              const int* __restrict__ goff,
                                              const float* __restrict__ fcw,
                                              const float* __restrict__ fcb,
                                              float* __restrict__ out, int G) {
    int g = blockIdx.x;
    int f = threadIdx.x;     // feature 0..127
    int s = goff[g], e = goff[g + 1];
    float m = -INFINITY, sum = 0.f;
    for (int node = s; node < e; ++node) {
        float v = h2[(size_t)node * 128 + f];
        m = fmaxf(m, v);
        sum += v;
    }
    int cnt = e - s;
    float maxp = (cnt > 0) ? m : 0.f;
    float cden = (float)(cnt > 0 ? cnt : 1);
    float meanp = sum / cden;
    float p = maxp * fcw[f] + meanp * fcw[128 + f];
    __shared__ float red[128];
    red[f] = p;
    __syncthreads();
    for (int off = 64; off; off >>= 1) {
        if (f < off) red[f] += red[f + off];
        __syncthreads();
    }
    if (f == 0) out[g] = red[0] + fcb[0];
}

extern "C" void kernel_launch(void* const* d_in, const int* in_sizes, int n_in,
                              void* d_out, int out_size, void* d_ws, size_t ws_size,
                              hipStream_t stream) {
    const int N = in_sizes[0] / 128;
    const int E = in_sizes[1] / 2;
    const int G = out_size;

    const float* x      = (const float*)d_in[0];
    const int*   ei     = (const int*)d_in[1];
    const int*   batch  = (const int*)d_in[2];
    const float* W1     = (const float*)d_in[3];
    const float* a_src1 = (const float*)d_in[4];
    const float* a_dst1 = (const float*)d_in[5];
    const float* b1     = (const float*)d_in[6];
    const float* W2     = (const float*)d_in[7];
    const float* a_src2 = (const float*)d_in[8];
    const float* a_dst2 = (const float*)d_in[9];
    const float* b2     = (const float*)d_in[10];
    const float* fcw    = (const float*)d_in[11];
    const float* fcb    = (const float*)d_in[12];
    float* out = (float*)d_out;

    // workspace carve (256B aligned)
    char* wp = (char*)d_ws;
    auto alloc = [&](size_t bytes) -> void* {
        void* p = (void*)wp;
        wp += (bytes + 255) & ~(size_t)255;
        return p;
    };
    const int EP = E + N;
    int* counts  = (int*)alloc(sizeof(int) * N);
    int* row_ptr = (int*)alloc(sizeof(int) * (N + 1));
    int* cursor  = (int*)alloc(sizeof(int) * (N + 1));
    int* col     = (int*)alloc(sizeof(int) * EP);
    int* gcount  = (int*)alloc(sizeof(int) * G);
    int* goff    = (int*)alloc(sizeof(int) * (G + 1));
    float* hp    = (float*)alloc(sizeof(float) * (size_t)N * 128);
    float* ha    = (float*)alloc(sizeof(float) * (size_t)N * 128);
    float* asv   = (float*)alloc(sizeof(float) * N);
    float* adv   = (float*)alloc(sizeof(float) * N);

    const int maxNG = (N > G) ? N : G;
    initk<<<(maxNG + 255) / 256, 256, 0, stream>>>(counts, gcount, N, G);
    {
        int m = (E > N) ? E : N;
        histk<<<(m + 255) / 256, 256, 0, stream>>>(ei, batch, counts, gcount, E, N);
    }
    scan_excl<<<1, 1024, 0, stream>>>(counts, row_ptr, cursor, N);
    scan_excl<<<1, 1024, 0, stream>>>(gcount, goff, nullptr, G);
    scatterk<<<(EP + 255) / 256, 256, 0, stream>>>(ei, cursor, col, E, N);

    const int gemmGrid = (N + 63) / 64;
    const int waveGrid = (N + 3) / 4;      // 4 waves per 256-thread block

    // layer 1 (input = relu(x))
    gemm128<<<gemmGrid, 256, 0, stream>>>(x, W1, hp, N, 1);
    rowdots<<<waveGrid, 256, 0, stream>>>(hp, a_src1, a_dst1, asv, adv, N);
    aggregate<<<waveGrid, 256, 0, stream>>>(hp, row_ptr, col, asv, adv, b1, ha, N);

    // layer 2 (input = ha, already relu'd)
    gemm128<<<gemmGrid, 256, 0, stream>>>(ha, W2, hp, N, 0);
    rowdots<<<waveGrid, 256, 0, stream>>>(hp, a_src2, a_dst2, asv, adv, N);
    aggregate<<<waveGrid, 256, 0, stream>>>(hp, row_ptr, col, asv, adv, b2, ha, N);

    // pooling + fc
    poolfc<<<G, 128, 0, stream>>>(ha, goff, fcw, fcb, out, G);
}

// Round 2
// 730.759 us; speedup vs baseline: 1.1993x; 1.1993x over previous
//
#include <hip/hip_runtime.h>
#include <math.h>

// ---------------------------------------------------------------------------
// GATRegressor: 2x GATConv(128->128, heads=1, self-loops) + max/mean pool + FC
// N=50000 nodes, E=1.6M edges, G=512 graphs. fp32 throughout.
// R2: aggregate rewritten for memory-level parallelism — edge metadata
// (col, softmax weight) cached in LDS during phase A; phase B issues 8
// independent 512B row loads per wave per iteration (was 1 serial chain).
// ---------------------------------------------------------------------------

#define LEAKY 0.2f

__global__ __launch_bounds__(256) void initk(int* counts, int* gcount, int N, int G) {
    int i = blockIdx.x * 256 + threadIdx.x;
    if (i < N) counts[i] = 1;            // self-loop per node
    if (i < G) gcount[i] = 0;
}

__global__ __launch_bounds__(256) void histk(const int* __restrict__ ei,
                                             const int* __restrict__ batch,
                                             int* counts, int* gcount, int E, int N) {
    int i = blockIdx.x * 256 + threadIdx.x;
    if (i < E) atomicAdd(&counts[ei[E + i]], 1);   // dst row of edge_index
    if (i < N) atomicAdd(&gcount[batch[i]], 1);
}

// single-block exclusive scan, n <= 1024*chunk. writes out[0..n] (out[n]=total),
// optionally mirrors into out2 (cursor copy).
__global__ __launch_bounds__(1024) void scan_excl(const int* __restrict__ in,
                                                  int* __restrict__ out,
                                                  int* __restrict__ out2, int n) {
    __shared__ int sh[1024];
    int t = threadIdx.x;
    int chunk = (n + 1023) >> 10;
    int begin = t * chunk;
    int fin = begin + chunk; if (fin > n) fin = n;
    int s = 0;
    for (int i = begin; i < fin; ++i) s += in[i];
    sh[t] = s;
    __syncthreads();
    for (int off = 1; off < 1024; off <<= 1) {
        int v = (t >= off) ? sh[t - off] : 0;
        __syncthreads();
        sh[t] += v;
        __syncthreads();
    }
    int run = sh[t] - s;   // exclusive prefix
    for (int i = begin; i < fin; ++i) {
        out[i] = run;
        if (out2) out2[i] = run;
        run += in[i];
    }
    if (t == 1023) { out[n] = sh[1023]; }
}

__global__ __launch_bounds__(256) void scatterk(const int* __restrict__ ei,
                                                int* cursor, int* col, int E, int N) {
    int i = blockIdx.x * 256 + threadIdx.x;
    if (i < E) {
        int s = ei[i];
        int d = ei[E + i];
        col[atomicAdd(&cursor[d], 1)] = s;
    } else if (i < E + N) {
        int v = i - E;
        col[atomicAdd(&cursor[v], 1)] = v;   // self loop
    }
}

// C[n x 128] = act(A[n x 128]) @ B[128 x 128]; applyRelu relus A on load.
__global__ __launch_bounds__(256) void gemm128(const float* __restrict__ A,
                                               const float* __restrict__ B,
                                               float* __restrict__ C,
                                               int n, int applyRelu) {
    __shared__ float As[64][33];     // [m][k], +1 pad
    __shared__ float Bs[32][132];    // [k][c], +4 pad
    const int tid = threadIdx.x;
    const int row0 = blockIdx.x * 64;
    const int tx = tid & 15;         // col group, TN=8
    const int ty = tid >> 4;         // row group, TM=4
    float acc[4][8] = {};

    for (int k0 = 0; k0 < 128; k0 += 32) {
        // A tile: 64 rows x 32 k. thread: r = tid>>3 (+32), kv = tid&7 (float4)
        {
            int kv = tid & 7, r = tid >> 3;
#pragma unroll
            for (int i = 0; i < 2; ++i) {
                int rr = r + 32 * i;
                int grow = row0 + rr;
                float4 v = make_float4(0.f, 0.f, 0.f, 0.f);
                if (grow < n) v = *(const float4*)(A + (size_t)grow * 128 + k0 + kv * 4);
                if (applyRelu) {
                    v.x = fmaxf(v.x, 0.f); v.y = fmaxf(v.y, 0.f);
                    v.z = fmaxf(v.z, 0.f); v.w = fmaxf(v.w, 0.f);
                }
                As[rr][kv * 4 + 0] = v.x; As[rr][kv * 4 + 1] = v.y;
                As[rr][kv * 4 + 2] = v.z; As[rr][kv * 4 + 3] = v.w;
            }
        }
        // B tile: 32 k x 128 c. thread: kr = tid>>5 (+8*i), cv = tid&31 (float4)
        {
            int cv = tid & 31, kr = tid >> 5;
#pragma unroll
            for (int i = 0; i < 4; ++i) {
                int kk = kr + 8 * i;
                float4 v = *(const float4*)(B + (size_t)(k0 + kk) * 128 + cv * 4);
                Bs[kk][cv * 4 + 0] = v.x; Bs[kk][cv * 4 + 1] = v.y;
                Bs[kk][cv * 4 + 2] = v.z; Bs[kk][cv * 4 + 3] = v.w;
            }
        }
        __syncthreads();
#pragma unroll
        for (int k = 0; k < 32; ++k) {
            float a[4], b[8];
#pragma unroll
            for (int i = 0; i < 4; ++i) a[i] = As[ty * 4 + i][k];
#pragma unroll
            for (int j = 0; j < 8; ++j) b[j] = Bs[k][tx * 8 + j];
#pragma unroll
            for (int i = 0; i < 4; ++i)
#pragma unroll
                for (int j = 0; j < 8; ++j) acc[i][j] += a[i] * b[j];
        }
        __syncthreads();
    }
#pragma unroll
    for (int i = 0; i < 4; ++i) {
        int grow = row0 + ty * 4 + i;
        if (grow < n) {
            float4* dst = (float4*)(C + (size_t)grow * 128 + tx * 8);
            dst[0] = make_float4(acc[i][0], acc[i][1], acc[i][2], acc[i][3]);
            dst[1] = make_float4(acc[i][4], acc[i][5], acc[i][6], acc[i][7]);
        }
    }
}

// asrc[r] = h'[r,:]·a_src ; adst[r] = h'[r,:]·a_dst. one wave per row.
__global__ __launch_bounds__(256) void rowdots(const float* __restrict__ hp,
                                               const float* __restrict__ a_src,
                                               const float* __restrict__ a_dst,
                                               float* __restrict__ asv,
                                               float* __restrict__ adv, int n) {
    int w = (blockIdx.x * 256 + threadIdx.x) >> 6;
    int lane = threadIdx.x & 63;
    if (w >= n) return;
    float2 v = *(const float2*)(hp + (size_t)w * 128 + 2 * lane);
    float2 as = ((const float2*)a_src)[lane];
    float2 ad = ((const float2*)a_dst)[lane];
    float ps = v.x * as.x + v.y * as.y;
    float pd = v.x * ad.x + v.y * ad.y;
#pragma unroll
    for (int off = 32; off; off >>= 1) {
        ps += __shfl_xor(ps, off, 64);
        pd += __shfl_xor(pd, off, 64);
    }
    if (lane == 0) { asv[w] = ps; adv[w] = pd; }
}

// one wave per dst node: segment softmax over incoming edges + weighted feature sum.
// Fast path (deg<=128): cols+weights cached in LDS; phase B issues 8
// independent row loads per iteration (masked tail batched too).
__global__ __launch_bounds__(256) void aggregate(const float* __restrict__ hp,
                                                 const int* __restrict__ rp,
                                                 const int* __restrict__ col,
                                                 const float* __restrict__ asv,
                                                 const float* __restrict__ adv,
                                                 const float* __restrict__ bias,
                                                 float* __restrict__ out, int n) {
    __shared__ int   scol[4][128];
    __shared__ float swt[4][128];
    const int wv = threadIdx.x >> 6;
    const int lane = threadIdx.x & 63;
    const int w = blockIdx.x * 4 + wv;
    if (w >= n) return;
    const int start = rp[w], end = rp[w + 1];
    const int deg = end - start;
    const float ad = adv[w];

    float2 acc = make_float2(0.f, 0.f);
    float inv;

    if (deg <= 128) {
        // ---- phase A: logits, wave max, exp-sum; stash (col, wgt) in LDS ----
        int c0 = 0, c1 = 0;
        float l0 = -INFINITY, l1 = -INFINITY;
        if (lane < deg) {
            c0 = col[start + lane];
            l0 = asv[c0] + ad;
            l0 = l0 > 0.f ? l0 : LEAKY * l0;
        }
        if (64 + lane < deg) {
            c1 = col[start + 64 + lane];
            l1 = asv[c1] + ad;
            l1 = l1 > 0.f ? l1 : LEAKY * l1;
        }
        float m = fmaxf(l0, l1);
#pragma unroll
        for (int off = 32; off; off >>= 1) m = fmaxf(m, __shfl_xor(m, off, 64));
        float e0 = (lane < deg) ? __expf(l0 - m) : 0.f;
        float e1 = (64 + lane < deg) ? __expf(l1 - m) : 0.f;
        float s = e0 + e1;
#pragma unroll
        for (int off = 32; off; off >>= 1) s += __shfl_xor(s, off, 64);
        inv = 1.f / s;
        if (lane < deg)      { scol[wv][lane] = c0;      swt[wv][lane] = e0; }
        if (64 + lane < deg) { scol[wv][64 + lane] = c1; swt[wv][64 + lane] = e1; }
        // same-wave LDS producer/consumer: no barrier needed (compiler waits lgkmcnt)

        // ---- phase B: 8 independent row loads in flight per iteration ----
        float2 aa[8];
#pragma unroll
        for (int j = 0; j < 8; ++j) aa[j] = make_float2(0.f, 0.f);
        const float* hpl = hp + 2 * lane;
        for (int i = 0; i < deg; i += 8) {
            int cs[8]; float ws[8];
#pragma unroll
            for (int j = 0; j < 8; ++j) {
                int idx = i + j;
                int cl = idx < deg ? idx : deg - 1;   // clamp: load valid row
                cs[j] = scol[wv][cl];
                ws[j] = (idx < deg) ? swt[wv][idx] : 0.f;  // mask via zero weight
            }
            float2 vs[8];
#pragma unroll
            for (int j = 0; j < 8; ++j)
                vs[j] = *(const float2*)(hpl + (size_t)cs[j] * 128);
#pragma unroll
            for (int j = 0; j < 8; ++j) {
                aa[j].x += ws[j] * vs[j].x;
                aa[j].y += ws[j] * vs[j].y;
            }
        }
#pragma unroll
        for (int j = 1; j < 8; ++j) { aa[0].x += aa[j].x; aa[0].y += aa[j].y; }
        acc = aa[0];
    } else {
        // ---- fallback for deg > 128 (not expected at this scale) ----
        float m = -INFINITY;
        for (int e = start + lane; e < end; e += 64) {
            float l = asv[col[e]] + ad;
            l = l > 0.f ? l : LEAKY * l;
            m = fmaxf(m, l);
        }
#pragma unroll
        for (int off = 32; off; off >>= 1) m = fmaxf(m, __shfl_xor(m, off, 64));
        float ssum = 0.f;
        for (int e = start + lane; e < end; e += 64) {
            float l = asv[col[e]] + ad;
            l = l > 0.f ? l : LEAKY * l;
            ssum += __expf(l - m);
        }
#pragma unroll
        for (int off = 32; off; off >>= 1) ssum += __shfl_xor(ssum, off, 64);
        inv = 1.f / ssum;
        for (int e = start; e < end; ++e) {
            int c = col[e];
            float l = asv[c] + ad;
            l = l > 0.f ? l : LEAKY * l;
            float wgt = __expf(l - m);
            float2 v = *(const float2*)(hp + (size_t)c * 128 + 2 * lane);
            acc.x += wgt * v.x;
            acc.y += wgt * v.y;
        }
    }

    float2 b = ((const float2*)bias)[lane];
    float2 o;
    o.x = fmaxf(acc.x * inv + b.x, 0.f);
    o.y = fmaxf(acc.y * inv + b.y, 0.f);
    *(float2*)(out + (size_t)w * 128 + 2 * lane) = o;
}

// one block (128 threads) per graph: max/mean pool over contiguous node range,
// then dot with fc_w (256) + fc_b.
__global__ __launch_bounds__(128) void poolfc(const float* __restrict__ h2,
                                              const int* __restrict__ goff,
                                              const float* __restrict__ fcw,
                                              const float* __restrict__ fcb,
                                              float* __restrict__ out, int G) {
    int g = blockIdx.x;
    int f = threadIdx.x;     // feature 0..127
    int s = goff[g], e = goff[g + 1];
    float m = -INFINITY, sum = 0.f;
    for (int node = s; node < e; ++node) {
        float v = h2[(size_t)node * 128 + f];
        m = fmaxf(m, v);
        sum += v;
    }
    int cnt = e - s;
    float maxp = (cnt > 0) ? m : 0.f;
    float cden = (float)(cnt > 0 ? cnt : 1);
    float meanp = sum / cden;
    float p = maxp * fcw[f] + meanp * fcw[128 + f];
    __shared__ float red[128];
    red[f] = p;
    __syncthreads();
    for (int off = 64; off; off >>= 1) {
        if (f < off) red[f] += red[f + off];
        __syncthreads();
    }
    if (f == 0) out[g] = red[0] + fcb[0];
}

extern "C" void kernel_launch(void* const* d_in, const int* in_sizes, int n_in,
                              void* d_out, int out_size, void* d_ws, size_t ws_size,
                              hipStream_t stream) {
    const int N = in_sizes[0] / 128;
    const int E = in_sizes[1] / 2;
    const int G = out_size;

    const float* x      = (const float*)d_in[0];
    const int*   ei     = (const int*)d_in[1];
    const int*   batch  = (const int*)d_in[2];
    const float* W1     = (const float*)d_in[3];
    const float* a_src1 = (const float*)d_in[4];
    const float* a_dst1 = (const float*)d_in[5];
    const float* b1     = (const float*)d_in[6];
    const float* W2     = (const float*)d_in[7];
    const float* a_src2 = (const float*)d_in[8];
    const float* a_dst2 = (const float*)d_in[9];
    const float* b2     = (const float*)d_in[10];
    const float* fcw    = (const float*)d_in[11];
    const float* fcb    = (const float*)d_in[12];
    float* out = (float*)d_out;

    // workspace carve (256B aligned)
    char* wp = (char*)d_ws;
    auto alloc = [&](size_t bytes) -> void* {
        void* p = (void*)wp;
        wp += (bytes + 255) & ~(size_t)255;
        return p;
    };
    const int EP = E + N;
    int* counts  = (int*)alloc(sizeof(int) * N);
    int* row_ptr = (int*)alloc(sizeof(int) * (N + 1));
    int* cursor  = (int*)alloc(sizeof(int) * (N + 1));
    int* col     = (int*)alloc(sizeof(int) * EP);
    int* gcount  = (int*)alloc(sizeof(int) * G);
    int* goff    = (int*)alloc(sizeof(int) * (G + 1));
    float* hp    = (float*)alloc(sizeof(float) * (size_t)N * 128);
    float* ha    = (float*)alloc(sizeof(float) * (size_t)N * 128);
    float* asv   = (float*)alloc(sizeof(float) * N);
    float* adv   = (float*)alloc(sizeof(float) * N);

    const int maxNG = (N > G) ? N : G;
    initk<<<(maxNG + 255) / 256, 256, 0, stream>>>(counts, gcount, N, G);
    {
        int m = (E > N) ? E : N;
        histk<<<(m + 255) / 256, 256, 0, stream>>>(ei, batch, counts, gcount, E, N);
    }
    scan_excl<<<1, 1024, 0, stream>>>(counts, row_ptr, cursor, N);
    scan_excl<<<1, 1024, 0, stream>>>(gcount, goff, nullptr, G);
    scatterk<<<(EP + 255) / 256, 256, 0, stream>>>(ei, cursor, col, E, N);

    const int gemmGrid = (N + 63) / 64;
    const int waveGrid = (N + 3) / 4;      // 4 waves per 256-thread block

    // layer 1 (input = relu(x))
    gemm128<<<gemmGrid, 256, 0, stream>>>(x, W1, hp, N, 1);
    rowdots<<<waveGrid, 256, 0, stream>>>(hp, a_src1, a_dst1, asv, adv, N);
    aggregate<<<waveGrid, 256, 0, stream>>>(hp, row_ptr, col, asv, adv, b1, ha, N);

    // layer 2 (input = ha, already relu'd)
    gemm128<<<gemmGrid, 256, 0, stream>>>(ha, W2, hp, N, 0);
    rowdots<<<waveGrid, 256, 0, stream>>>(hp, a_src2, a_dst2, asv, adv, N);
    aggregate<<<waveGrid, 256, 0, stream>>>(hp, row_ptr, col, asv, adv, b2, ha, N);

    // pooling + fc
    poolfc<<<G, 128, 0, stream>>>(ha, goff, fcw, fcb, out, G);
}

// Round 3
// 693.721 us; speedup vs baseline: 1.2634x; 1.0534x over previous
//
#include <hip/hip_runtime.h>
#include <math.h>

// ---------------------------------------------------------------------------
// GATRegressor: 2x GATConv(128->128, heads=1, self-loops) + max/mean pool + FC
// N=50000 nodes, E=1.6M edges, G=512 graphs. fp32 throughout.
// R3: CSR build via two-pass counting sort (binA: edges -> 64-node dst
// buckets, binB: bucket -> exact col position with LDS cursors). Kills the
// 16x write amplification of the old random 4B scatter (102MB -> ~20MB).
// ---------------------------------------------------------------------------

#define LEAKY 0.2f

__global__ __launch_bounds__(256) void initk(int* counts, int* gcount, int N, int G) {
    int i = blockIdx.x * 256 + threadIdx.x;
    if (i < N) counts[i] = 1;            // self-loop per node
    if (i < G) gcount[i] = 0;
}

__global__ __launch_bounds__(256) void histk(const int* __restrict__ ei,
                                             const int* __restrict__ batch,
                                             int* counts, int* gcount, int E, int N) {
    int i = blockIdx.x * 256 + threadIdx.x;
    if (i < E) atomicAdd(&counts[ei[E + i]], 1);   // dst row of edge_index
    if (i < N) atomicAdd(&gcount[batch[i]], 1);
}

// single-block exclusive scan, n <= 1024*chunk. writes out[0..n] (out[n]=total).
__global__ __launch_bounds__(1024) void scan_excl(const int* __restrict__ in,
                                                  int* __restrict__ out, int n) {
    __shared__ int sh[1024];
    int t = threadIdx.x;
    int chunk = (n + 1023) >> 10;
    int begin = t * chunk;
    int fin = begin + chunk; if (fin > n) fin = n;
    int s = 0;
    for (int i = begin; i < fin; ++i) s += in[i];
    sh[t] = s;
    __syncthreads();
    for (int off = 1; off < 1024; off <<= 1) {
        int v = (t >= off) ? sh[t - off] : 0;
        __syncthreads();
        sh[t] += v;
        __syncthreads();
    }
    int run = sh[t] - s;   // exclusive prefix
    for (int i = begin; i < fin; ++i) {
        out[i] = run;
        run += in[i];
    }
    if (t == 1023) { out[n] = sh[1023]; }
}

// bucket cursors: one per 64B line (stride 16 ints) to avoid per-line
// atomic serialization. bstart[b] = rp[64b] - 64b (self-loops excluded).
__global__ __launch_bounds__(256) void initbc(const int* __restrict__ rp,
                                              int* __restrict__ bcursor, int NB) {
    int b = blockIdx.x * 256 + threadIdx.x;
    if (b < NB) bcursor[b * 16] = rp[b * 64] - b * 64;
}

// Pass A: scatter (dst,src) pairs into dst/64 buckets. Write frontier is
// ~782 lines (~50KB) -> full-line write combining.
__global__ __launch_bounds__(256) void binA(const int* __restrict__ ei,
                                            int* __restrict__ bcursor,
                                            int2* __restrict__ pairs, int E) {
    int i = blockIdx.x * 256 + threadIdx.x;
    if (i >= E) return;
    int s = ei[i];
    int d = ei[E + i];
    int pos = atomicAdd(&bcursor[(d >> 6) * 16], 1);
    pairs[pos] = make_int2(d, s);
}

// Pass B: one block per bucket; LDS cursors for the bucket's 64 nodes;
// scatter src into the bucket's contiguous col window (~8.7KB).
__global__ __launch_bounds__(256) void binB(const int2* __restrict__ pairs,
                                            const int* __restrict__ rp,
                                            int* __restrict__ col, int N) {
    __shared__ int cur[64];
    const int b = blockIdx.x;
    const int n0 = b * 64;
    int n1 = n0 + 64; if (n1 > N) n1 = N;
    const int t = threadIdx.x;
    if (t < n1 - n0) {
        int v = n0 + t;
        int base = rp[v];
        col[base] = v;          // self-loop at slot 0
        cur[t] = base + 1;
    }
    __syncthreads();
    const int e0 = rp[n0] - n0;        // bucket pair range
    const int e1 = rp[n1] - n1;
    for (int e = e0 + t; e < e1; e += 256) {
        int2 p = pairs[e];             // x=dst, y=src
        int pos = atomicAdd(&cur[p.x - n0], 1);
        col[pos] = p.y;
    }
}

// C[n x 128] = act(A[n x 128]) @ B[128 x 128]; applyRelu relus A on load.
__global__ __launch_bounds__(256) void gemm128(const float* __restrict__ A,
                                               const float* __restrict__ B,
                                               float* __restrict__ C,
                                               int n, int applyRelu) {
    __shared__ float As[64][33];     // [m][k], +1 pad
    __shared__ float Bs[32][132];    // [k][c], +4 pad
    const int tid = threadIdx.x;
    const int row0 = blockIdx.x * 64;
    const int tx = tid & 15;         // col group, TN=8
    const int ty = tid >> 4;         // row group, TM=4
    float acc[4][8] = {};

    for (int k0 = 0; k0 < 128; k0 += 32) {
        {
            int kv = tid & 7, r = tid >> 3;
#pragma unroll
            for (int i = 0; i < 2; ++i) {
                int rr = r + 32 * i;
                int grow = row0 + rr;
                float4 v = make_float4(0.f, 0.f, 0.f, 0.f);
                if (grow < n) v = *(const float4*)(A + (size_t)grow * 128 + k0 + kv * 4);
                if (applyRelu) {
                    v.x = fmaxf(v.x, 0.f); v.y = fmaxf(v.y, 0.f);
                    v.z = fmaxf(v.z, 0.f); v.w = fmaxf(v.w, 0.f);
                }
                As[rr][kv * 4 + 0] = v.x; As[rr][kv * 4 + 1] = v.y;
                As[rr][kv * 4 + 2] = v.z; As[rr][kv * 4 + 3] = v.w;
            }
        }
        {
            int cv = tid & 31, kr = tid >> 5;
#pragma unroll
            for (int i = 0; i < 4; ++i) {
                int kk = kr + 8 * i;
                float4 v = *(const float4*)(B + (size_t)(k0 + kk) * 128 + cv * 4);
                Bs[kk][cv * 4 + 0] = v.x; Bs[kk][cv * 4 + 1] = v.y;
                Bs[kk][cv * 4 + 2] = v.z; Bs[kk][cv * 4 + 3] = v.w;
            }
        }
        __syncthreads();
#pragma unroll
        for (int k = 0; k < 32; ++k) {
            float a[4], b[8];
#pragma unroll
            for (int i = 0; i < 4; ++i) a[i] = As[ty * 4 + i][k];
#pragma unroll
            for (int j = 0; j < 8; ++j) b[j] = Bs[k][tx * 8 + j];
#pragma unroll
            for (int i = 0; i < 4; ++i)
#pragma unroll
                for (int j = 0; j < 8; ++j) acc[i][j] += a[i] * b[j];
        }
        __syncthreads();
    }
#pragma unroll
    for (int i = 0; i < 4; ++i) {
        int grow = row0 + ty * 4 + i;
        if (grow < n) {
            float4* dst = (float4*)(C + (size_t)grow * 128 + tx * 8);
            dst[0] = make_float4(acc[i][0], acc[i][1], acc[i][2], acc[i][3]);
            dst[1] = make_float4(acc[i][4], acc[i][5], acc[i][6], acc[i][7]);
        }
    }
}

// asrc[r] = h'[r,:]·a_src ; adst[r] = h'[r,:]·a_dst. one wave per row.
__global__ __launch_bounds__(256) void rowdots(const float* __restrict__ hp,
                                               const float* __restrict__ a_src,
                                               const float* __restrict__ a_dst,
                                               float* __restrict__ asv,
                                               float* __restrict__ adv, int n) {
    int w = (blockIdx.x * 256 + threadIdx.x) >> 6;
    int lane = threadIdx.x & 63;
    if (w >= n) return;
    float2 v = *(const float2*)(hp + (size_t)w * 128 + 2 * lane);
    float2 as = ((const float2*)a_src)[lane];
    float2 ad = ((const float2*)a_dst)[lane];
    float ps = v.x * as.x + v.y * as.y;
    float pd = v.x * ad.x + v.y * ad.y;
#pragma unroll
    for (int off = 32; off; off >>= 1) {
        ps += __shfl_xor(ps, off, 64);
        pd += __shfl_xor(pd, off, 64);
    }
    if (lane == 0) { asv[w] = ps; adv[w] = pd; }
}

// one wave per dst node: segment softmax over incoming edges + weighted feature sum.
__global__ __launch_bounds__(256) void aggregate(const float* __restrict__ hp,
                                                 const int* __restrict__ rp,
                                                 const int* __restrict__ col,
                                                 const float* __restrict__ asv,
                                                 const float* __restrict__ adv,
                                                 const float* __restrict__ bias,
                                                 float* __restrict__ out, int n) {
    __shared__ int   scol[4][128];
    __shared__ float swt[4][128];
    const int wv = threadIdx.x >> 6;
    const int lane = threadIdx.x & 63;
    const int w = blockIdx.x * 4 + wv;
    if (w >= n) return;
    const int start = rp[w], end = rp[w + 1];
    const int deg = end - start;
    const float ad = adv[w];

    float2 acc = make_float2(0.f, 0.f);
    float inv;

    if (deg <= 128) {
        int c0 = 0, c1 = 0;
        float l0 = -INFINITY, l1 = -INFINITY;
        if (lane < deg) {
            c0 = col[start + lane];
            l0 = asv[c0] + ad;
            l0 = l0 > 0.f ? l0 : LEAKY * l0;
        }
        if (64 + lane < deg) {
            c1 = col[start + 64 + lane];
            l1 = asv[c1] + ad;
            l1 = l1 > 0.f ? l1 : LEAKY * l1;
        }
        float m = fmaxf(l0, l1);
#pragma unroll
        for (int off = 32; off; off >>= 1) m = fmaxf(m, __shfl_xor(m, off, 64));
        float e0 = (lane < deg) ? __expf(l0 - m) : 0.f;
        float e1 = (64 + lane < deg) ? __expf(l1 - m) : 0.f;
        float s = e0 + e1;
#pragma unroll
        for (int off = 32; off; off >>= 1) s += __shfl_xor(s, off, 64);
        inv = 1.f / s;
        if (lane < deg)      { scol[wv][lane] = c0;      swt[wv][lane] = e0; }
        if (64 + lane < deg) { scol[wv][64 + lane] = c1; swt[wv][64 + lane] = e1; }
        // same-wave LDS producer/consumer: wave-synchronous, no barrier needed

        float2 aa[8];
#pragma unroll
        for (int j = 0; j < 8; ++j) aa[j] = make_float2(0.f, 0.f);
        const float* hpl = hp + 2 * lane;
        for (int i = 0; i < deg; i += 8) {
            int cs[8]; float ws[8];
#pragma unroll
            for (int j = 0; j < 8; ++j) {
                int idx = i + j;
                int cl = idx < deg ? idx : deg - 1;
                cs[j] = scol[wv][cl];
                ws[j] = (idx < deg) ? swt[wv][idx] : 0.f;
            }
            float2 vs[8];
#pragma unroll
            for (int j = 0; j < 8; ++j)
                vs[j] = *(const float2*)(hpl + (size_t)cs[j] * 128);
#pragma unroll
            for (int j = 0; j < 8; ++j) {
                aa[j].x += ws[j] * vs[j].x;
                aa[j].y += ws[j] * vs[j].y;
            }
        }
#pragma unroll
        for (int j = 1; j < 8; ++j) { aa[0].x += aa[j].x; aa[0].y += aa[j].y; }
        acc = aa[0];
    } else {
        float m = -INFINITY;
        for (int e = start + lane; e < end; e += 64) {
            float l = asv[col[e]] + ad;
            l = l > 0.f ? l : LEAKY * l;
            m = fmaxf(m, l);
        }
#pragma unroll
        for (int off = 32; off; off >>= 1) m = fmaxf(m, __shfl_xor(m, off, 64));
        float ssum = 0.f;
        for (int e = start + lane; e < end; e += 64) {
            float l = asv[col[e]] + ad;
            l = l > 0.f ? l : LEAKY * l;
            ssum += __expf(l - m);
        }
#pragma unroll
        for (int off = 32; off; off >>= 1) ssum += __shfl_xor(ssum, off, 64);
        inv = 1.f / ssum;
        for (int e = start; e < end; ++e) {
            int c = col[e];
            float l = asv[c] + ad;
            l = l > 0.f ? l : LEAKY * l;
            float wgt = __expf(l - m);
            float2 v = *(const float2*)(hp + (size_t)c * 128 + 2 * lane);
            acc.x += wgt * v.x;
            acc.y += wgt * v.y;
        }
    }

    float2 b = ((const float2*)bias)[lane];
    float2 o;
    o.x = fmaxf(acc.x * inv + b.x, 0.f);
    o.y = fmaxf(acc.y * inv + b.y, 0.f);
    *(float2*)(out + (size_t)w * 128 + 2 * lane) = o;
}

// one block (128 threads) per graph: max/mean pool + fc dot.
__global__ __launch_bounds__(128) void poolfc(const float* __restrict__ h2,
                                              const int* __restrict__ goff,
                                              const float* __restrict__ fcw,
                                              const float* __restrict__ fcb,
                                              float* __restrict__ out, int G) {
    int g = blockIdx.x;
    int f = threadIdx.x;
    int s = goff[g], e = goff[g + 1];
    float m = -INFINITY, sum = 0.f;
    for (int node = s; node < e; ++node) {
        float v = h2[(size_t)node * 128 + f];
        m = fmaxf(m, v);
        sum += v;
    }
    int cnt = e - s;
    float maxp = (cnt > 0) ? m : 0.f;
    float cden = (float)(cnt > 0 ? cnt : 1);
    float meanp = sum / cden;
    float p = maxp * fcw[f] + meanp * fcw[128 + f];
    __shared__ float red[128];
    red[f] = p;
    __syncthreads();
    for (int off = 64; off; off >>= 1) {
        if (f < off) red[f] += red[f + off];
        __syncthreads();
    }
    if (f == 0) out[g] = red[0] + fcb[0];
}

extern "C" void kernel_launch(void* const* d_in, const int* in_sizes, int n_in,
                              void* d_out, int out_size, void* d_ws, size_t ws_size,
                              hipStream_t stream) {
    const int N = in_sizes[0] / 128;
    const int E = in_sizes[1] / 2;
    const int G = out_size;
    const int NB = (N + 63) / 64;          // dst buckets (64 nodes each)

    const float* x      = (const float*)d_in[0];
    const int*   ei     = (const int*)d_in[1];
    const int*   batch  = (const int*)d_in[2];
    const float* W1     = (const float*)d_in[3];
    const float* a_src1 = (const float*)d_in[4];
    const float* a_dst1 = (const float*)d_in[5];
    const float* b1     = (const float*)d_in[6];
    const float* W2     = (const float*)d_in[7];
    const float* a_src2 = (const float*)d_in[8];
    const float* a_dst2 = (const float*)d_in[9];
    const float* b2     = (const float*)d_in[10];
    const float* fcw    = (const float*)d_in[11];
    const float* fcb    = (const float*)d_in[12];
    float* out = (float*)d_out;

    // workspace carve (256B aligned)
    char* wp = (char*)d_ws;
    auto alloc = [&](size_t bytes) -> void* {
        void* p = (void*)wp;
        wp += (bytes + 255) & ~(size_t)255;
        return p;
    };
    const int EP = E + N;
    int* counts  = (int*)alloc(sizeof(int) * N);
    int* row_ptr = (int*)alloc(sizeof(int) * (N + 1));
    int* bcursor = (int*)alloc(sizeof(int) * NB * 16);   // 1 counter / 64B line
    int* col     = (int*)alloc(sizeof(int) * EP);
    int* gcount  = (int*)alloc(sizeof(int) * G);
    int* goff    = (int*)alloc(sizeof(int) * (G + 1));
    float* hp    = (float*)alloc(sizeof(float) * (size_t)N * 128);
    float* ha    = (float*)alloc(sizeof(float) * (size_t)N * 128);
    float* asv   = (float*)alloc(sizeof(float) * N);
    float* adv   = (float*)alloc(sizeof(float) * N);
    int2* pairs  = (int2*)hp;   // alias: pairs dead before gemm writes hp

    const int maxNG = (N > G) ? N : G;
    initk<<<(maxNG + 255) / 256, 256, 0, stream>>>(counts, gcount, N, G);
    {
        int m = (E > N) ? E : N;
        histk<<<(m + 255) / 256, 256, 0, stream>>>(ei, batch, counts, gcount, E, N);
    }
    scan_excl<<<1, 1024, 0, stream>>>(counts, row_ptr, N);
    scan_excl<<<1, 1024, 0, stream>>>(gcount, goff, G);
    initbc<<<(NB + 255) / 256, 256, 0, stream>>>(row_ptr, bcursor, NB);
    binA<<<(E + 255) / 256, 256, 0, stream>>>(ei, bcursor, pairs, E);
    binB<<<NB, 256, 0, stream>>>(pairs, row_ptr, col, N);

    const int gemmGrid = (N + 63) / 64;
    const int waveGrid = (N + 3) / 4;      // 4 waves per 256-thread block

    // layer 1 (input = relu(x))
    gemm128<<<gemmGrid, 256, 0, stream>>>(x, W1, hp, N, 1);
    rowdots<<<waveGrid, 256, 0, stream>>>(hp, a_src1, a_dst1, asv, adv, N);
    aggregate<<<waveGrid, 256, 0, stream>>>(hp, row_ptr, col, asv, adv, b1, ha, N);

    // layer 2 (input = ha, already relu'd)
    gemm128<<<gemmGrid, 256, 0, stream>>>(ha, W2, hp, N, 0);
    rowdots<<<waveGrid, 256, 0, stream>>>(hp, a_src2, a_dst2, asv, adv, N);
    aggregate<<<waveGrid, 256, 0, stream>>>(hp, row_ptr, col, asv, adv, b2, ha, N);

    // pooling + fc
    poolfc<<<G, 128, 0, stream>>>(ha, goff, fcw, fcb, out, G);
}

// Round 4
// 659.243 us; speedup vs baseline: 1.3294x; 1.0523x over previous
//
#include <hip/hip_runtime.h>
#include <math.h>

// ---------------------------------------------------------------------------
// GATRegressor: 2x GATConv(128->128, heads=1, self-loops) + max/mean pool + FC
// N=50000 nodes, E=1.6M edges, G=512 graphs. fp32 throughout.
// R4: CSR scatter partitioned by XCD (blockIdx&7 under round-robin dispatch):
// every col cache line is written by one XCD only -> full-line combining in
// that XCD's L2 (R3 showed 7x write amplification from cross-XCD sharing).
// rowdots fused into gemm epilogue (saves 2 dispatches + 51MB rereads).
// ---------------------------------------------------------------------------

#define LEAKY 0.2f

__global__ __launch_bounds__(256) void initk(int* counts, int* gcount, int N, int G) {
    int i = blockIdx.x * 256 + threadIdx.x;
    if (i < N) counts[i] = 1;            // self-loop per node
    if (i < G) gcount[i] = 0;
}

__global__ __launch_bounds__(256) void histk(const int* __restrict__ ei,
                                             const int* __restrict__ batch,
                                             int* counts, int* gcount, int E, int N) {
    int i = blockIdx.x * 256 + threadIdx.x;
    if (i < E) atomicAdd(&counts[ei[E + i]], 1);   // dst row of edge_index
    if (i < N) atomicAdd(&gcount[batch[i]], 1);
}

// single-block exclusive scan, n <= 1024*chunk. writes out[0..n] (out[n]=total).
__global__ __launch_bounds__(1024) void scan_excl(const int* __restrict__ in,
                                                  int* __restrict__ out, int n) {
    __shared__ int sh[1024];
    int t = threadIdx.x;
    int chunk = (n + 1023) >> 10;
    int begin = t * chunk;
    int fin = begin + chunk; if (fin > n) fin = n;
    int s = 0;
    for (int i = begin; i < fin; ++i) s += in[i];
    sh[t] = s;
    __syncthreads();
    for (int off = 1; off < 1024; off <<= 1) {
        int v = (t >= off) ? sh[t - off] : 0;
        __syncthreads();
        sh[t] += v;
        __syncthreads();
    }
    int run = sh[t] - s;   // exclusive prefix
    for (int i = begin; i < fin; ++i) {
        out[i] = run;
        run += in[i];
    }
    if (t == 1023) { out[n] = sh[1023]; }
}

// self-loop at slot rp[v]; cursor starts just past it.
__global__ __launch_bounds__(256) void initcur(const int* __restrict__ rp,
                                               int* __restrict__ cursor,
                                               int* __restrict__ col, int N) {
    int v = blockIdx.x * 256 + threadIdx.x;
    if (v < N) {
        int b = rp[v];
        col[b] = v;
        cursor[v] = b + 1;
    }
}

// XCD-partitioned scatter. Partition g = blockIdx&7 owns dst range
// [g*N/8,(g+1)*N/8); 8 blocks (round-robin -> 8 XCDs) share each 4096-edge
// chunk, each keeping only its own range. Writes to a col line then come
// from a single XCD -> full-line combining. Correct regardless of mapping.
__global__ __launch_bounds__(256) void scatterx(const int* __restrict__ ei,
                                                int* __restrict__ cursor,
                                                int* __restrict__ col,
                                                int E, int N) {
    const int g = blockIdx.x & 7;
    const int chunk = blockIdx.x >> 3;
    const int lo = (int)(((long long)N * g) >> 3);
    const int hi = (int)(((long long)N * (g + 1)) >> 3);
    const int base = chunk * 4096;
    int fin = base + 4096; if (fin > E) fin = E;
    for (int i = base + threadIdx.x; i < fin; i += 256) {
        int d = ei[E + i];
        if (d >= lo && d < hi) {
            int s = ei[i];
            col[atomicAdd(&cursor[d], 1)] = s;
        }
    }
}

// C[n x 128] = act(A[n x 128]) @ B[128 x 128]; applyRelu relus A on load.
// Fused epilogue: asv[r] = C[r,:]·a_src, adv[r] = C[r,:]·a_dst.
__global__ __launch_bounds__(256) void gemm128(const float* __restrict__ A,
                                               const float* __restrict__ B,
                                               float* __restrict__ C,
                                               const float* __restrict__ a_src,
                                               const float* __restrict__ a_dst,
                                               float* __restrict__ asv,
                                               float* __restrict__ adv,
                                               int n, int applyRelu) {
    __shared__ float As[64][33];     // [m][k], +1 pad
    __shared__ float Bs[32][132];    // [k][c], +4 pad
    __shared__ float sredS[64][17];  // rowdot partials (16 tx groups, +1 pad)
    __shared__ float sredD[64][17];
    const int tid = threadIdx.x;
    const int row0 = blockIdx.x * 64;
    const int tx = tid & 15;         // col group, TN=8
    const int ty = tid >> 4;         // row group, TM=4
    float acc[4][8] = {};

    for (int k0 = 0; k0 < 128; k0 += 32) {
        {
            int kv = tid & 7, r = tid >> 3;
#pragma unroll
            for (int i = 0; i < 2; ++i) {
                int rr = r + 32 * i;
                int grow = row0 + rr;
                float4 v = make_float4(0.f, 0.f, 0.f, 0.f);
                if (grow < n) v = *(const float4*)(A + (size_t)grow * 128 + k0 + kv * 4);
                if (applyRelu) {
                    v.x = fmaxf(v.x, 0.f); v.y = fmaxf(v.y, 0.f);
                    v.z = fmaxf(v.z, 0.f); v.w = fmaxf(v.w, 0.f);
                }
                As[rr][kv * 4 + 0] = v.x; As[rr][kv * 4 + 1] = v.y;
                As[rr][kv * 4 + 2] = v.z; As[rr][kv * 4 + 3] = v.w;
            }
        }
        {
            int cv = tid & 31, kr = tid >> 5;
#pragma unroll
            for (int i = 0; i < 4; ++i) {
                int kk = kr + 8 * i;
                float4 v = *(const float4*)(B + (size_t)(k0 + kk) * 128 + cv * 4);
                Bs[kk][cv * 4 + 0] = v.x; Bs[kk][cv * 4 + 1] = v.y;
                Bs[kk][cv * 4 + 2] = v.z; Bs[kk][cv * 4 + 3] = v.w;
            }
        }
        __syncthreads();
#pragma unroll
        for (int k = 0; k < 32; ++k) {
            float a[4], b[8];
#pragma unroll
            for (int i = 0; i < 4; ++i) a[i] = As[ty * 4 + i][k];
#pragma unroll
            for (int j = 0; j < 8; ++j) b[j] = Bs[k][tx * 8 + j];
#pragma unroll
            for (int i = 0; i < 4; ++i)
#pragma unroll
                for (int j = 0; j < 8; ++j) acc[i][j] += a[i] * b[j];
        }
        __syncthreads();
    }

    // store C + rowdot partials
    float asl[8], adl[8];
#pragma unroll
    for (int j = 0; j < 8; ++j) {
        asl[j] = a_src[tx * 8 + j];
        adl[j] = a_dst[tx * 8 + j];
    }
#pragma unroll
    for (int i = 0; i < 4; ++i) {
        int rr = ty * 4 + i;
        int grow = row0 + rr;
        float ps = 0.f, pd = 0.f;
#pragma unroll
        for (int j = 0; j < 8; ++j) {
            ps += acc[i][j] * asl[j];
            pd += acc[i][j] * adl[j];
        }
        sredS[rr][tx] = ps;
        sredD[rr][tx] = pd;
        if (grow < n) {
            float4* dst = (float4*)(C + (size_t)grow * 128 + tx * 8);
            dst[0] = make_float4(acc[i][0], acc[i][1], acc[i][2], acc[i][3]);
            dst[1] = make_float4(acc[i][4], acc[i][5], acc[i][6], acc[i][7]);
        }
    }
    __syncthreads();
    if (tid < 64) {
        int grow = row0 + tid;
        if (grow < n) {
            float ps = 0.f, pd = 0.f;
#pragma unroll
            for (int j = 0; j < 16; ++j) {
                ps += sredS[tid][j];
                pd += sredD[tid][j];
            }
            asv[grow] = ps;
            adv[grow] = pd;
        }
    }
}

// one wave per dst node: segment softmax over incoming edges + weighted feature sum.
__global__ __launch_bounds__(256) void aggregate(const float* __restrict__ hp,
                                                 const int* __restrict__ rp,
                                                 const int* __restrict__ col,
                                                 const float* __restrict__ asv,
                                                 const float* __restrict__ adv,
                                                 const float* __restrict__ bias,
                                                 float* __restrict__ out, int n) {
    __shared__ int   scol[4][128];
    __shared__ float swt[4][128];
    const int wv = threadIdx.x >> 6;
    const int lane = threadIdx.x & 63;
    const int w = blockIdx.x * 4 + wv;
    if (w >= n) return;
    const int start = rp[w], end = rp[w + 1];
    const int deg = end - start;
    const float ad = adv[w];

    float2 acc = make_float2(0.f, 0.f);
    float inv;

    if (deg <= 128) {
        int c0 = 0, c1 = 0;
        float l0 = -INFINITY, l1 = -INFINITY;
        if (lane < deg) {
            c0 = col[start + lane];
            l0 = asv[c0] + ad;
            l0 = l0 > 0.f ? l0 : LEAKY * l0;
        }
        if (64 + lane < deg) {
            c1 = col[start + 64 + lane];
            l1 = asv[c1] + ad;
            l1 = l1 > 0.f ? l1 : LEAKY * l1;
        }
        float m = fmaxf(l0, l1);
#pragma unroll
        for (int off = 32; off; off >>= 1) m = fmaxf(m, __shfl_xor(m, off, 64));
        float e0 = (lane < deg) ? __expf(l0 - m) : 0.f;
        float e1 = (64 + lane < deg) ? __expf(l1 - m) : 0.f;
        float s = e0 + e1;
#pragma unroll
        for (int off = 32; off; off >>= 1) s += __shfl_xor(s, off, 64);
        inv = 1.f / s;
        if (lane < deg)      { scol[wv][lane] = c0;      swt[wv][lane] = e0; }
        if (64 + lane < deg) { scol[wv][64 + lane] = c1; swt[wv][64 + lane] = e1; }
        // same-wave LDS producer/consumer: wave-synchronous, no barrier needed

        float2 aa[8];
#pragma unroll
        for (int j = 0; j < 8; ++j) aa[j] = make_float2(0.f, 0.f);
        const float* hpl = hp + 2 * lane;
        for (int i = 0; i < deg; i += 8) {
            int cs[8]; float ws[8];
#pragma unroll
            for (int j = 0; j < 8; ++j) {
                int idx = i + j;
                int cl = idx < deg ? idx : deg - 1;
                cs[j] = scol[wv][cl];
                ws[j] = (idx < deg) ? swt[wv][idx] : 0.f;
            }
            float2 vs[8];
#pragma unroll
            for (int j = 0; j < 8; ++j)
                vs[j] = *(const float2*)(hpl + (size_t)cs[j] * 128);
#pragma unroll
            for (int j = 0; j < 8; ++j) {
                aa[j].x += ws[j] * vs[j].x;
                aa[j].y += ws[j] * vs[j].y;
            }
        }
#pragma unroll
        for (int j = 1; j < 8; ++j) { aa[0].x += aa[j].x; aa[0].y += aa[j].y; }
        acc = aa[0];
    } else {
        float m = -INFINITY;
        for (int e = start + lane; e < end; e += 64) {
            float l = asv[col[e]] + ad;
            l = l > 0.f ? l : LEAKY * l;
            m = fmaxf(m, l);
        }
#pragma unroll
        for (int off = 32; off; off >>= 1) m = fmaxf(m, __shfl_xor(m, off, 64));
        float ssum = 0.f;
        for (int e = start + lane; e < end; e += 64) {
            float l = asv[col[e]] + ad;
            l = l > 0.f ? l : LEAKY * l;
            ssum += __expf(l - m);
        }
#pragma unroll
        for (int off = 32; off; off >>= 1) ssum += __shfl_xor(ssum, off, 64);
        inv = 1.f / ssum;
        for (int e = start; e < end; ++e) {
            int c = col[e];
            float l = asv[c] + ad;
            l = l > 0.f ? l : LEAKY * l;
            float wgt = __expf(l - m);
            float2 v = *(const float2*)(hp + (size_t)c * 128 + 2 * lane);
            acc.x += wgt * v.x;
            acc.y += wgt * v.y;
        }
    }

    float2 b = ((const float2*)bias)[lane];
    float2 o;
    o.x = fmaxf(acc.x * inv + b.x, 0.f);
    o.y = fmaxf(acc.y * inv + b.y, 0.f);
    *(float2*)(out + (size_t)w * 128 + 2 * lane) = o;
}

// one block (128 threads) per graph: max/mean pool + fc dot.
__global__ __launch_bounds__(128) void poolfc(const float* __restrict__ h2,
                                              const int* __restrict__ goff,
                                              const float* __restrict__ fcw,
                                              const float* __restrict__ fcb,
                                              float* __restrict__ out, int G) {
    int g = blockIdx.x;
    int f = threadIdx.x;
    int s = goff[g], e = goff[g + 1];
    float m = -INFINITY, sum = 0.f;
    for (int node = s; node < e; ++node) {
        float v = h2[(size_t)node * 128 + f];
        m = fmaxf(m, v);
        sum += v;
    }
    int cnt = e - s;
    float maxp = (cnt > 0) ? m : 0.f;
    float cden = (float)(cnt > 0 ? cnt : 1);
    float meanp = sum / cden;
    float p = maxp * fcw[f] + meanp * fcw[128 + f];
    __shared__ float red[128];
    red[f] = p;
    __syncthreads();
    for (int off = 64; off; off >>= 1) {
        if (f < off) red[f] += red[f + off];
        __syncthreads();
    }
    if (f == 0) out[g] = red[0] + fcb[0];
}

extern "C" void kernel_launch(void* const* d_in, const int* in_sizes, int n_in,
                              void* d_out, int out_size, void* d_ws, size_t ws_size,
                              hipStream_t stream) {
    const int N = in_sizes[0] / 128;
    const int E = in_sizes[1] / 2;
    const int G = out_size;

    const float* x      = (const float*)d_in[0];
    const int*   ei     = (const int*)d_in[1];
    const int*   batch  = (const int*)d_in[2];
    const float* W1     = (const float*)d_in[3];
    const float* a_src1 = (const float*)d_in[4];
    const float* a_dst1 = (const float*)d_in[5];
    const float* b1     = (const float*)d_in[6];
    const float* W2     = (const float*)d_in[7];
    const float* a_src2 = (const float*)d_in[8];
    const float* a_dst2 = (const float*)d_in[9];
    const float* b2     = (const float*)d_in[10];
    const float* fcw    = (const float*)d_in[11];
    const float* fcb    = (const float*)d_in[12];
    float* out = (float*)d_out;

    // workspace carve (256B aligned)
    char* wp = (char*)d_ws;
    auto alloc = [&](size_t bytes) -> void* {
        void* p = (void*)wp;
        wp += (bytes + 255) & ~(size_t)255;
        return p;
    };
    const int EP = E + N;
    int* counts  = (int*)alloc(sizeof(int) * N);
    int* row_ptr = (int*)alloc(sizeof(int) * (N + 1));
    int* cursor  = (int*)alloc(sizeof(int) * N);
    int* col     = (int*)alloc(sizeof(int) * EP);
    int* gcount  = (int*)alloc(sizeof(int) * G);
    int* goff    = (int*)alloc(sizeof(int) * (G + 1));
    float* hp    = (float*)alloc(sizeof(float) * (size_t)N * 128);
    float* ha    = (float*)alloc(sizeof(float) * (size_t)N * 128);
    float* asv   = (float*)alloc(sizeof(float) * N);
    float* adv   = (float*)alloc(sizeof(float) * N);

    const int maxNG = (N > G) ? N : G;
    initk<<<(maxNG + 255) / 256, 256, 0, stream>>>(counts, gcount, N, G);
    {
        int m = (E > N) ? E : N;
        histk<<<(m + 255) / 256, 256, 0, stream>>>(ei, batch, counts, gcount, E, N);
    }
    scan_excl<<<1, 1024, 0, stream>>>(counts, row_ptr, N);
    scan_excl<<<1, 1024, 0, stream>>>(gcount, goff, G);
    initcur<<<(N + 255) / 256, 256, 0, stream>>>(row_ptr, cursor, col, N);
    {
        int nchunk = (E + 4095) / 4096;
        scatterx<<<nchunk * 8, 256, 0, stream>>>(ei, cursor, col, E, N);
    }

    const int gemmGrid = (N + 63) / 64;
    const int waveGrid = (N + 3) / 4;      // 4 waves per 256-thread block

    // layer 1 (input = relu(x)); gemm fuses rowdots epilogue
    gemm128<<<gemmGrid, 256, 0, stream>>>(x, W1, hp, a_src1, a_dst1, asv, adv, N, 1);
    aggregate<<<waveGrid, 256, 0, stream>>>(hp, row_ptr, col, asv, adv, b1, ha, N);

    // layer 2 (input = ha, already relu'd)
    gemm128<<<gemmGrid, 256, 0, stream>>>(ha, W2, hp, a_src2, a_dst2, asv, adv, N, 0);
    aggregate<<<waveGrid, 256, 0, stream>>>(hp, row_ptr, col, asv, adv, b2, ha, N);

    // pooling + fc
    poolfc<<<G, 128, 0, stream>>>(ha, goff, fcw, fcb, out, G);
}

// Round 5
// 609.009 us; speedup vs baseline: 1.4391x; 1.0825x over previous
//
#include <hip/hip_runtime.h>
#include <math.h>

// ---------------------------------------------------------------------------
// GATRegressor: 2x GATConv(128->128, heads=1, self-loops) + max/mean pool + FC
// N=50000 nodes, E=1.6M edges, G=512 graphs. fp32 throughout.
// R5: (a) aggregate phase B uses half-wave float4 row loads -> 16 rows
// (8KB) in flight per wave (was 8 rows/4KB); (b) serial single-block scans
// replaced by 3-phase parallel scan (blocksum/midscan/localscan), with
// initcur fused into localscan.
// ---------------------------------------------------------------------------

#define LEAKY 0.2f
#define SEG 4096

__global__ __launch_bounds__(256) void initk(int* counts, int* gcount, int N, int G) {
    int i = blockIdx.x * 256 + threadIdx.x;
    if (i < N) counts[i] = 1;            // self-loop per node
    if (i < G) gcount[i] = 0;
}

__global__ __launch_bounds__(256) void histk(const int* __restrict__ ei,
                                             const int* __restrict__ batch,
                                             int* counts, int* gcount, int E, int N) {
    int i = blockIdx.x * 256 + threadIdx.x;
    if (i < E) atomicAdd(&counts[ei[E + i]], 1);   // dst row of edge_index
    if (i < N) atomicAdd(&gcount[batch[i]], 1);
}

// phase 1: per-4096-segment sums of counts.
__global__ __launch_bounds__(256) void blocksum(const int* __restrict__ counts,
                                                int* __restrict__ bsum, int N) {
    __shared__ int sh[256];
    const int t = threadIdx.x;
    const int base = blockIdx.x * SEG + t * 16;
    int s = 0;
#pragma unroll
    for (int k = 0; k < 16; ++k) {
        int i = base + k;
        if (i < N) s += counts[i];
    }
    sh[t] = s;
    __syncthreads();
    for (int off = 128; off; off >>= 1) {
        if (t < off) sh[t] += sh[t + off];
        __syncthreads();
    }
    if (t == 0) bsum[blockIdx.x] = sh[0];
}

// phase 2 (1 block): scan gcount -> goff, scan bsum -> boff, row_ptr[N]=total.
__global__ __launch_bounds__(1024) void midscan(const int* __restrict__ gcount,
                                                int* __restrict__ goff,
                                                const int* __restrict__ bsum,
                                                int* __restrict__ boff,
                                                int* __restrict__ row_ptr,
                                                int nb, int G, int N) {
    __shared__ int sh[1024];
    const int t = threadIdx.x;
    int v = (t < G) ? gcount[t] : 0;
    sh[t] = v;
    __syncthreads();
    for (int off = 1; off < 1024; off <<= 1) {
        int u = (t >= off) ? sh[t - off] : 0;
        __syncthreads();
        sh[t] += u;
        __syncthreads();
    }
    if (t < G) goff[t] = sh[t] - v;
    if (t == G - 1) goff[G] = sh[t];
    if (t == 0) {
        int run = 0;
        for (int b = 0; b < nb; ++b) { boff[b] = run; run += bsum[b]; }
        row_ptr[N] = run;
    }
}

// phase 3: per-segment local exclusive scan + boff; fused initcur (cursor,
// self-loop into col).
__global__ __launch_bounds__(256) void localscan(const int* __restrict__ counts,
                                                 const int* __restrict__ boff,
                                                 int* __restrict__ row_ptr,
                                                 int* __restrict__ cursor,
                                                 int* __restrict__ col, int N) {
    __shared__ int sh[256];
    const int t = threadIdx.x;
    const int base = blockIdx.x * SEG + t * 16;
    int v[16];
    int s = 0;
#pragma unroll
    for (int k = 0; k < 16; ++k) {
        int i = base + k;
        v[k] = (i < N) ? counts[i] : 0;
        s += v[k];
    }
    sh[t] = s;
    __syncthreads();
    for (int off = 1; off < 256; off <<= 1) {
        int u = (t >= off) ? sh[t - off] : 0;
        __syncthreads();
        sh[t] += u;
        __syncthreads();
    }
    int run = boff[blockIdx.x] + sh[t] - s;   // exclusive prefix for this thread
#pragma unroll
    for (int k = 0; k < 16; ++k) {
        int i = base + k;
        if (i < N) {
            row_ptr[i] = run;
            cursor[i] = run + 1;
            col[run] = i;          // self-loop at slot 0
        }
        run += v[k];
    }
}

// XCD-partitioned scatter (see R4 note): partition g=blockIdx&7 owns dst
// range [g*N/8,(g+1)*N/8) so each col line is written from one XCD only.
__global__ __launch_bounds__(256) void scatterx(const int* __restrict__ ei,
                                                int* __restrict__ cursor,
                                                int* __restrict__ col,
                                                int E, int N) {
    const int g = blockIdx.x & 7;
    const int chunk = blockIdx.x >> 3;
    const int lo = (int)(((long long)N * g) >> 3);
    const int hi = (int)(((long long)N * (g + 1)) >> 3);
    const int base = chunk * 4096;
    int fin = base + 4096; if (fin > E) fin = E;
    for (int i = base + threadIdx.x; i < fin; i += 256) {
        int d = ei[E + i];
        if (d >= lo && d < hi) {
            int s = ei[i];
            col[atomicAdd(&cursor[d], 1)] = s;
        }
    }
}

// C[n x 128] = act(A[n x 128]) @ B[128 x 128]; applyRelu relus A on load.
// Fused epilogue: asv[r] = C[r,:]·a_src, adv[r] = C[r,:]·a_dst.
__global__ __launch_bounds__(256) void gemm128(const float* __restrict__ A,
                                               const float* __restrict__ B,
                                               float* __restrict__ C,
                                               const float* __restrict__ a_src,
                                               const float* __restrict__ a_dst,
                                               float* __restrict__ asv,
                                               float* __restrict__ adv,
                                               int n, int applyRelu) {
    __shared__ float As[64][33];     // [m][k], +1 pad
    __shared__ float Bs[32][132];    // [k][c], +4 pad
    __shared__ float sredS[64][17];  // rowdot partials (16 tx groups, +1 pad)
    __shared__ float sredD[64][17];
    const int tid = threadIdx.x;
    const int row0 = blockIdx.x * 64;
    const int tx = tid & 15;         // col group, TN=8
    const int ty = tid >> 4;         // row group, TM=4
    float acc[4][8] = {};

    for (int k0 = 0; k0 < 128; k0 += 32) {
        {
            int kv = tid & 7, r = tid >> 3;
#pragma unroll
            for (int i = 0; i < 2; ++i) {
                int rr = r + 32 * i;
                int grow = row0 + rr;
                float4 v = make_float4(0.f, 0.f, 0.f, 0.f);
                if (grow < n) v = *(const float4*)(A + (size_t)grow * 128 + k0 + kv * 4);
                if (applyRelu) {
                    v.x = fmaxf(v.x, 0.f); v.y = fmaxf(v.y, 0.f);
                    v.z = fmaxf(v.z, 0.f); v.w = fmaxf(v.w, 0.f);
                }
                As[rr][kv * 4 + 0] = v.x; As[rr][kv * 4 + 1] = v.y;
                As[rr][kv * 4 + 2] = v.z; As[rr][kv * 4 + 3] = v.w;
            }
        }
        {
            int cv = tid & 31, kr = tid >> 5;
#pragma unroll
            for (int i = 0; i < 4; ++i) {
                int kk = kr + 8 * i;
                float4 v = *(const float4*)(B + (size_t)(k0 + kk) * 128 + cv * 4);
                Bs[kk][cv * 4 + 0] = v.x; Bs[kk][cv * 4 + 1] = v.y;
                Bs[kk][cv * 4 + 2] = v.z; Bs[kk][cv * 4 + 3] = v.w;
            }
        }
        __syncthreads();
#pragma unroll
        for (int k = 0; k < 32; ++k) {
            float a[4], b[8];
#pragma unroll
            for (int i = 0; i < 4; ++i) a[i] = As[ty * 4 + i][k];
#pragma unroll
            for (int j = 0; j < 8; ++j) b[j] = Bs[k][tx * 8 + j];
#pragma unroll
            for (int i = 0; i < 4; ++i)
#pragma unroll
                for (int j = 0; j < 8; ++j) acc[i][j] += a[i] * b[j];
        }
        __syncthreads();
    }

    // store C + rowdot partials
    float asl[8], adl[8];
#pragma unroll
    for (int j = 0; j < 8; ++j) {
        asl[j] = a_src[tx * 8 + j];
        adl[j] = a_dst[tx * 8 + j];
    }
#pragma unroll
    for (int i = 0; i < 4; ++i) {
        int rr = ty * 4 + i;
        int grow = row0 + rr;
        float ps = 0.f, pd = 0.f;
#pragma unroll
        for (int j = 0; j < 8; ++j) {
            ps += acc[i][j] * asl[j];
            pd += acc[i][j] * adl[j];
        }
        sredS[rr][tx] = ps;
        sredD[rr][tx] = pd;
        if (grow < n) {
            float4* dst = (float4*)(C + (size_t)grow * 128 + tx * 8);
            dst[0] = make_float4(acc[i][0], acc[i][1], acc[i][2], acc[i][3]);
            dst[1] = make_float4(acc[i][4], acc[i][5], acc[i][6], acc[i][7]);
        }
    }
    __syncthreads();
    if (tid < 64) {
        int grow = row0 + tid;
        if (grow < n) {
            float ps = 0.f, pd = 0.f;
#pragma unroll
            for (int j = 0; j < 16; ++j) {
                ps += sredS[tid][j];
                pd += sredD[tid][j];
            }
            asv[grow] = ps;
            adv[grow] = pd;
        }
    }
}

// one wave per dst node: segment softmax + weighted feature sum.
// Phase B: half-wave float4 rows -> 16 rows (8KB) in flight per wave.
__global__ __launch_bounds__(256) void aggregate(const float* __restrict__ hp,
                                                 const int* __restrict__ rp,
                                                 const int* __restrict__ col,
                                                 const float* __restrict__ asv,
                                                 const float* __restrict__ adv,
                                                 const float* __restrict__ bias,
                                                 float* __restrict__ out, int n) {
    __shared__ int   scol[4][128];
    __shared__ float swt[4][128];
    const int wv = threadIdx.x >> 6;
    const int lane = threadIdx.x & 63;
    const int w = blockIdx.x * 4 + wv;
    if (w >= n) return;
    const int start = rp[w], end = rp[w + 1];
    const int deg = end - start;
    const float ad = adv[w];

    if (deg <= 128) {
        // ---- phase A: logits, wave max, exp-sum; stash (col, wgt) in LDS ----
        int c0 = 0, c1 = 0;
        float l0 = -INFINITY, l1 = -INFINITY;
        if (lane < deg) {
            c0 = col[start + lane];
            l0 = asv[c0] + ad;
            l0 = l0 > 0.f ? l0 : LEAKY * l0;
        }
        if (64 + lane < deg) {
            c1 = col[start + 64 + lane];
            l1 = asv[c1] + ad;
            l1 = l1 > 0.f ? l1 : LEAKY * l1;
        }
        float m = fmaxf(l0, l1);
#pragma unroll
        for (int off = 32; off; off >>= 1) m = fmaxf(m, __shfl_xor(m, off, 64));
        float e0 = (lane < deg) ? __expf(l0 - m) : 0.f;
        float e1 = (64 + lane < deg) ? __expf(l1 - m) : 0.f;
        float s = e0 + e1;
#pragma unroll
        for (int off = 32; off; off >>= 1) s += __shfl_xor(s, off, 64);
        float inv = 1.f / s;
        if (lane < deg)      { scol[wv][lane] = c0;      swt[wv][lane] = e0; }
        if (64 + lane < deg) { scol[wv][64 + lane] = c1; swt[wv][64 + lane] = e1; }
        // same-wave LDS producer/consumer: wave-synchronous, no barrier needed

        // ---- phase B: half-wave float4 rows, 16 edges per iteration ----
        const int hw = lane >> 5;        // half-wave 0/1
        const int sl = lane & 31;        // sub-lane: feature group [4sl..4sl+4)
        float4 aa[8];
#pragma unroll
        for (int j = 0; j < 8; ++j) aa[j] = make_float4(0.f, 0.f, 0.f, 0.f);
        for (int i = 0; i < deg; i += 16) {
            int cs[8]; float ws[8];
#pragma unroll
            for (int j = 0; j < 8; ++j) {
                int idx = i + 2 * j + hw;
                int cl = idx < deg ? idx : deg - 1;   // clamp: load valid row
                cs[j] = scol[wv][cl];
                ws[j] = (idx < deg) ? swt[wv][idx] : 0.f;  // mask via zero wgt
            }
            float4 vs[8];
#pragma unroll
            for (int j = 0; j < 8; ++j)
                vs[j] = *((const float4*)(hp + (size_t)cs[j] * 128) + sl);
#pragma unroll
            for (int j = 0; j < 8; ++j) {
                aa[j].x += ws[j] * vs[j].x;
                aa[j].y += ws[j] * vs[j].y;
                aa[j].z += ws[j] * vs[j].z;
                aa[j].w += ws[j] * vs[j].w;
            }
        }
#pragma unroll
        for (int j = 1; j < 8; ++j) {
            aa[0].x += aa[j].x; aa[0].y += aa[j].y;
            aa[0].z += aa[j].z; aa[0].w += aa[j].w;
        }
        // cross-half combine: lane and lane^32 hold same feature group
        aa[0].x += __shfl_xor(aa[0].x, 32);
        aa[0].y += __shfl_xor(aa[0].y, 32);
        aa[0].z += __shfl_xor(aa[0].z, 32);
        aa[0].w += __shfl_xor(aa[0].w, 32);
        if (hw == 0) {
            float4 b = ((const float4*)bias)[sl];
            float4 o;
            o.x = fmaxf(aa[0].x * inv + b.x, 0.f);
            o.y = fmaxf(aa[0].y * inv + b.y, 0.f);
            o.z = fmaxf(aa[0].z * inv + b.z, 0.f);
            o.w = fmaxf(aa[0].w * inv + b.w, 0.f);
            *((float4*)(out + (size_t)w * 128) + sl) = o;
        }
    } else {
        // ---- fallback for deg > 128 (not expected at this scale) ----
        float m = -INFINITY;
        for (int e = start + lane; e < end; e += 64) {
            float l = asv[col[e]] + ad;
            l = l > 0.f ? l : LEAKY * l;
            m = fmaxf(m, l);
        }
#pragma unroll
        for (int off = 32; off; off >>= 1) m = fmaxf(m, __shfl_xor(m, off, 64));
        float ssum = 0.f;
        for (int e = start + lane; e < end; e += 64) {
            float l = asv[col[e]] + ad;
            l = l > 0.f ? l : LEAKY * l;
            ssum += __expf(l - m);
        }
#pragma unroll
        for (int off = 32; off; off >>= 1) ssum += __shfl_xor(ssum, off, 64);
        float inv = 1.f / ssum;
        float2 acc = make_float2(0.f, 0.f);
        for (int e = start; e < end; ++e) {
            int c = col[e];
            float l = asv[c] + ad;
            l = l > 0.f ? l : LEAKY * l;
            float wgt = __expf(l - m);
            float2 v = *(const float2*)(hp + (size_t)c * 128 + 2 * lane);
            acc.x += wgt * v.x;
            acc.y += wgt * v.y;
        }
        float2 b = ((const float2*)bias)[lane];
        float2 o;
        o.x = fmaxf(acc.x * inv + b.x, 0.f);
        o.y = fmaxf(acc.y * inv + b.y, 0.f);
        *(float2*)(out + (size_t)w * 128 + 2 * lane) = o;
    }
}

// one block (128 threads) per graph: max/mean pool + fc dot.
__global__ __launch_bounds__(128) void poolfc(const float* __restrict__ h2,
                                              const int* __restrict__ goff,
                                              const float* __restrict__ fcw,
                                              const float* __restrict__ fcb,
                                              float* __restrict__ out, int G) {
    int g = blockIdx.x;
    int f = threadIdx.x;
    int s = goff[g], e = goff[g + 1];
    float m = -INFINITY, sum = 0.f;
    for (int node = s; node < e; ++node) {
        float v = h2[(size_t)node * 128 + f];
        m = fmaxf(m, v);
        sum += v;
    }
    int cnt = e - s;
    float maxp = (cnt > 0) ? m : 0.f;
    float cden = (float)(cnt > 0 ? cnt : 1);
    float meanp = sum / cden;
    float p = maxp * fcw[f] + meanp * fcw[128 + f];
    __shared__ float red[128];
    red[f] = p;
    __syncthreads();
    for (int off = 64; off; off >>= 1) {
        if (f < off) red[f] += red[f + off];
        __syncthreads();
    }
    if (f == 0) out[g] = red[0] + fcb[0];
}

extern "C" void kernel_launch(void* const* d_in, const int* in_sizes, int n_in,
                              void* d_out, int out_size, void* d_ws, size_t ws_size,
                              hipStream_t stream) {
    const int N = in_sizes[0] / 128;
    const int E = in_sizes[1] / 2;
    const int G = out_size;
    const int nb = (N + SEG - 1) / SEG;

    const float* x      = (const float*)d_in[0];
    const int*   ei     = (const int*)d_in[1];
    const int*   batch  = (const int*)d_in[2];
    const float* W1     = (const float*)d_in[3];
    const float* a_src1 = (const float*)d_in[4];
    const float* a_dst1 = (const float*)d_in[5];
    const float* b1     = (const float*)d_in[6];
    const float* W2     = (const float*)d_in[7];
    const float* a_src2 = (const float*)d_in[8];
    const float* a_dst2 = (const float*)d_in[9];
    const float* b2     = (const float*)d_in[10];
    const float* fcw    = (const float*)d_in[11];
    const float* fcb    = (const float*)d_in[12];
    float* out = (float*)d_out;

    // workspace carve (256B aligned)
    char* wp = (char*)d_ws;
    auto alloc = [&](size_t bytes) -> void* {
        void* p = (void*)wp;
        wp += (bytes + 255) & ~(size_t)255;
        return p;
    };
    const int EP = E + N;
    int* counts  = (int*)alloc(sizeof(int) * N);
    int* row_ptr = (int*)alloc(sizeof(int) * (N + 1));
    int* cursor  = (int*)alloc(sizeof(int) * N);
    int* col     = (int*)alloc(sizeof(int) * EP);
    int* gcount  = (int*)alloc(sizeof(int) * G);
    int* goff    = (int*)alloc(sizeof(int) * (G + 1));
    int* bsum    = (int*)alloc(sizeof(int) * nb);
    int* boff    = (int*)alloc(sizeof(int) * nb);
    float* hp    = (float*)alloc(sizeof(float) * (size_t)N * 128);
    float* ha    = (float*)alloc(sizeof(float) * (size_t)N * 128);
    float* asv   = (float*)alloc(sizeof(float) * N);
    float* adv   = (float*)alloc(sizeof(float) * N);

    const int maxNG = (N > G) ? N : G;
    initk<<<(maxNG + 255) / 256, 256, 0, stream>>>(counts, gcount, N, G);
    {
        int m = (E > N) ? E : N;
        histk<<<(m + 255) / 256, 256, 0, stream>>>(ei, batch, counts, gcount, E, N);
    }
    blocksum<<<nb, 256, 0, stream>>>(counts, bsum, N);
    midscan<<<1, 1024, 0, stream>>>(gcount, goff, bsum, boff, row_ptr, nb, G, N);
    localscan<<<nb, 256, 0, stream>>>(counts, boff, row_ptr, cursor, col, N);
    {
        int nchunk = (E + 4095) / 4096;
        scatterx<<<nchunk * 8, 256, 0, stream>>>(ei, cursor, col, E, N);
    }

    const int gemmGrid = (N + 63) / 64;
    const int waveGrid = (N + 3) / 4;      // 4 waves per 256-thread block

    // layer 1 (input = relu(x)); gemm fuses rowdots epilogue
    gemm128<<<gemmGrid, 256, 0, stream>>>(x, W1, hp, a_src1, a_dst1, asv, adv, N, 1);
    aggregate<<<waveGrid, 256, 0, stream>>>(hp, row_ptr, col, asv, adv, b1, ha, N);

    // layer 2 (input = ha, already relu'd)
    gemm128<<<gemmGrid, 256, 0, stream>>>(ha, W2, hp, a_src2, a_dst2, asv, adv, N, 0);
    aggregate<<<waveGrid, 256, 0, stream>>>(hp, row_ptr, col, asv, adv, b2, ha, N);

    // pooling + fc
    poolfc<<<G, 128, 0, stream>>>(ha, goff, fcw, fcb, out, G);
}